// Round 6
// baseline (239.000 us; speedup 1.0000x reference)
//
#include <hip/hip_runtime.h>

typedef __bf16 bf16x8 __attribute__((ext_vector_type(8)));
typedef float  f32x4  __attribute__((ext_vector_type(4)));
typedef unsigned short u16x8 __attribute__((ext_vector_type(8)));
typedef unsigned short USHORT;

__device__ __forceinline__ USHORT f2bf(float f) {
    unsigned u = __float_as_uint(f);
    u += 0x7fffu + ((u >> 16) & 1u);
    return (USHORT)(u >> 16);
}

__device__ __forceinline__ float bf2f(USHORT v) {
    return __uint_as_float((unsigned)v << 16);
}

__device__ __forceinline__ f32x4 fz4() { f32x4 z = {0.f, 0.f, 0.f, 0.f}; return z; }

__device__ __forceinline__ bf16x8 ldbf8(const USHORT* p) { return *(const bf16x8*)p; }

__device__ __forceinline__ f32x4 mfma16(bf16x8 a, bf16x8 b, f32x4 c) {
    return __builtin_amdgcn_mfma_f32_16x16x32_bf16(a, b, c, 0, 0, 0);
}

// async global->LDS, 16B per lane; LDS dest is wave-uniform base + lane*16
__device__ __forceinline__ void gload_lds16(const void* g, void* s) {
    __builtin_amdgcn_global_load_lds(
        (const __attribute__((address_space(1))) unsigned int*)g,
        (__attribute__((address_space(3))) unsigned int*)s, 16, 0, 0);
}

// per-wave LDS ordering fence (wave-private LDS region). sched_barrier after the
// waitcnt per guide rule #18.
__device__ __forceinline__ void lds_fence() {
    asm volatile("s_waitcnt lgkmcnt(0)" ::: "memory");
    __builtin_amdgcn_sched_barrier(0);
}

// ---------------- merged prep: X fp32->bf16 + both W transposes ----------------
__global__ __launch_bounds__(256) void prep_kernel(const float* __restrict__ X,
                                                   const float* __restrict__ Wqkv,
                                                   const float* __restrict__ Wout,
                                                   USHORT* __restrict__ Xb,
                                                   USHORT* __restrict__ Wt1,
                                                   USHORT* __restrict__ Wt3) {
    int bid = blockIdx.x;
    if (bid < 2048) {
        int base = (bid * 256 + threadIdx.x) * 8;
        float4 a = *(const float4*)(X + base);
        float4 b = *(const float4*)(X + base + 4);
        u16x8 o;
        o[0] = f2bf(a.x); o[1] = f2bf(a.y); o[2] = f2bf(a.z); o[3] = f2bf(a.w);
        o[4] = f2bf(b.x); o[5] = f2bf(b.y); o[6] = f2bf(b.z); o[7] = f2bf(b.w);
        *(u16x8*)(Xb + base) = o;
    } else if (bid < 3328) {
        int t = (bid - 2048) * 256 + threadIdx.x;   // 0..327679 : 640x512
        int k = t & 511, n = t >> 9;
        Wt1[t] = f2bf(Wqkv[(size_t)k * 1536 + n]);
    } else {
        int t = (bid - 3328) * 256 + threadIdx.x;   // 0..262143 : 512x512
        int k = t & 511, n = t >> 9;
        Wt3[t] = f2bf(Wout[(size_t)k * 512 + n]);
    }
}

// ---------------- 4-way partial-ctx reduce: o = bf16(sum fp32(parts)) ----------
// In-place safe with o == a (each thread reads its 8 elems before writing them).
__global__ __launch_bounds__(256) void reduce4(const USHORT* __restrict__ a,
                                               const USHORT* __restrict__ b,
                                               const USHORT* __restrict__ c,
                                               const USHORT* __restrict__ d,
                                               USHORT* __restrict__ o) {
    int base = (blockIdx.x * 256 + threadIdx.x) * 8;
    u16x8 va = *(const u16x8*)(a + base);
    u16x8 vb = *(const u16x8*)(b + base);
    u16x8 vc = *(const u16x8*)(c + base);
    u16x8 vd = *(const u16x8*)(d + base);
    u16x8 out;
#pragma unroll
    for (int j = 0; j < 8; ++j)
        out[j] = f2bf(bf2f(va[j]) + bf2f(vb[j]) + bf2f(vc[j]) + bf2f(vd[j]));
    *(u16x8*)(o + base) = out;
}

// ---------------- m97-style bf16 GEMM: C = A(MxK) * Bt(NxK)^T -------------------
template <bool BF16OUT>
__global__ __launch_bounds__(256) void gemm_bt(const USHORT* __restrict__ A,
                                               const USHORT* __restrict__ Bt,
                                               void* __restrict__ Cv,
                                               int M, int N, int K) {
    __shared__ __align__(16) USHORT Asm[128 * 32];
    __shared__ __align__(16) USHORT Bsm[128 * 32];
    const int tid = threadIdx.x;
    const int wv = tid >> 6, ln = tid & 63;
    const int l16 = ln & 15, quad = ln >> 4;
    const int m0 = blockIdx.x * 128, n0 = blockIdx.y * 128;
    const int wm = (wv >> 1) * 64, wn = (wv & 1) * 64;

    f32x4 acc[4][4];
#pragma unroll
    for (int i = 0; i < 4; ++i)
#pragma unroll
        for (int j = 0; j < 4; ++j) acc[i][j] = fz4();

    const int kTiles = K >> 5;
    for (int kt = 0; kt < kTiles; ++kt) {
        __syncthreads();
#pragma unroll
        for (int i = 0; i < 2; ++i) {
            int cb = wv * 128 + i * 64;
            int c = cb + ln;
            gload_lds16(A + (size_t)(m0 + (c >> 2)) * K + kt * 32 + (c & 3) * 8,
                        &Asm[cb * 8]);
            gload_lds16(Bt + (size_t)(n0 + (c >> 2)) * K + kt * 32 + (c & 3) * 8,
                        &Bsm[cb * 8]);
        }
        __syncthreads();

        bf16x8 af[4], bfr[4];
#pragma unroll
        for (int i = 0; i < 4; ++i)
            af[i] = ldbf8(&Asm[(wm + i * 16 + l16) * 32 + quad * 8]);
#pragma unroll
        for (int j = 0; j < 4; ++j)
            bfr[j] = ldbf8(&Bsm[(wn + j * 16 + l16) * 32 + quad * 8]);
#pragma unroll
        for (int i = 0; i < 4; ++i)
#pragma unroll
            for (int j = 0; j < 4; ++j)
                acc[i][j] = mfma16(af[i], bfr[j], acc[i][j]);
    }

#pragma unroll
    for (int i = 0; i < 4; ++i)
#pragma unroll
        for (int j = 0; j < 4; ++j)
#pragma unroll
            for (int r = 0; r < 4; ++r) {
                size_t row = m0 + wm + i * 16 + quad * 4 + r;
                size_t col = n0 + wn + j * 16 + l16;
                if (BF16OUT)
                    ((USHORT*)Cv)[row * N + col] = f2bf(acc[i][j][r]);
                else
                    ((float*)Cv)[row * N + col] = acc[i][j][r];
            }
}

// ---------------- V transpose: Vt[((b*8+h)*64+d)*1024+k] = P[(b*1024+k)*640+(h+2)*64+d]
__global__ __launch_bounds__(256) void transpose_v(const USHORT* __restrict__ P,
                                                   USHORT* __restrict__ Vt) {
    __shared__ __align__(16) USHORT T[64][72];
    const int t = threadIdx.x;
    const int k0 = blockIdx.x * 64;
    const int hh = blockIdx.y;
    const int b = blockIdx.z;
#pragma unroll
    for (int i = 0; i < 2; ++i) {
        int c = i * 256 + t;
        int kk = c >> 3, d8 = (c & 7) * 8;
        u16x8 v = *(const u16x8*)(P + (size_t)((b << 10) + k0 + kk) * 640 +
                                  (hh + 2) * 64 + d8);
        *(u16x8*)&T[kk][d8] = v;
    }
    __syncthreads();
#pragma unroll
    for (int i = 0; i < 2; ++i) {
        int d = (t >> 3) + i * 32;
        int kk0 = (t & 7) * 8;
        u16x8 v;
#pragma unroll
        for (int j = 0; j < 8; ++j) v[j] = T[kk0 + j][d];
        *(u16x8*)(Vt + (size_t)(((b << 3) + hh) * 64 + d) * 1024 + k0 + kk0) = v;
    }
}

// ---------------- fused attention v7 -------------------------------------------
// = v6 (shared K/V staging, conflict-free LDS map, double-buffer, partial-buffer
// stores) + two fixes driven by r5 PMC (WRITE 182MB vs 33.5MB payload):
//
// (1) FULL-LINE EPILOGUE STORES. v6's scalar 2B stores covered only 32B per row
//     per instruction; a 128B line needed 4 stores ~12 instructions apart ->
//     partial-sector writebacks + line fills under L2 thrash. Now each wave
//     transposes its 16q x 64d oacc tile (per b) through a wave-private LDS
//     scratch (reusing the DEAD Kl region after the k-loop) and stores full
//     128B-aligned rows: one u16x8 per lane, 8 lanes per row -> every store
//     instruction covers 8 complete lines.
// (2) __launch_bounds__(512, 2): lifts the register cap from the compiler's
//     128 (chosen for a 2-blocks/CU occupancy the 256-block grid can never
//     use) to 256, removing any scratch spill traffic. Grid = 1 block/CU
//     regardless (r5 occupancy 21% confirms), so no occupancy cost.
__global__ __launch_bounds__(512, 2) void attn_kernel(const USHORT* __restrict__ P,
                                                      const USHORT* __restrict__ Vt,
                                                      USHORT* __restrict__ pt0,
                                                      USHORT* __restrict__ pt1,
                                                      USHORT* __restrict__ pt2,
                                                      USHORT* __restrict__ pt3) {
    const int h = blockIdx.x;
    const int qb = blockIdx.y;
    const int kc = blockIdx.z;                    // 0..3, 256 keys each
    const int tid = threadIdx.x;
    const int wv = tid >> 6;                      // 0..7
    const int lane = tid & 63;
    const int l16 = lane & 15, quad = lane >> 4;
    const int q0 = qb * 128 + wv * 16;

    // Kl chunk map per (b,ks) 2KB region: off16B = (key>>4)*64 + piece*16 + (key&15)
    // Vl chunk map per (b)    4KB region: off16B = (d>>4)*64  + piece*16 + (d&15)
    __shared__ __align__(16) USHORT Kl[2][16384];     // 64KB
    __shared__ __align__(16) USHORT Vl[2][16384];     // 64KB
    __shared__ __align__(16) USHORT alds[8][16][40];  // per-wave tile 10KB
    USHORT (*aw)[40] = alds[wv];

    // Q fragments: A[m=l16 (q-row)][k=ks*32+quad*8+j]
    bf16x8 qf[8][2];
#pragma unroll
    for (int b = 0; b < 8; ++b)
#pragma unroll
        for (int ks = 0; ks < 2; ++ks)
            qf[b][ks] = ldbf8(P + (size_t)((b << 10) + q0 + l16) * 640 + h * 64 +
                              ks * 32 + quad * 8);

    f32x4 oacc[8][4];
#pragma unroll
    for (int b = 0; b < 8; ++b)
#pragma unroll
        for (int nt = 0; nt < 4; ++nt) oacc[b][nt] = fz4();

    // ---- staging: 64 gload_lds total (8/wave); wv<4 -> K, wv>=4 -> V ----
    // K instr (b,ks,half): lane s loads (key=half*16+(s&15), piece=s>>4)
    //   -> dest chunks half*64 + s  (contiguous 1KB, wave-uniform base)
    // V instr (b,dq):      lane s loads (d = dq*16+(s&15),  piece=s>>4)
    auto stage = [&](int k0s, int buf) {
        if (wv < 4) {
#pragma unroll
            for (int i = 0; i < 8; ++i) {
                int g = wv * 8 + i;
                int b = g >> 2, ks = (g >> 1) & 1, half = g & 1;
                gload_lds16(P + (size_t)((b << 10) + k0s + half * 16 + (lane & 15)) * 640 +
                                (h + 1) * 64 + ks * 32 + (lane >> 4) * 8,
                            &Kl[buf][(b * 2 + ks) * 1024 + half * 512]);
            }
        } else {
#pragma unroll
            for (int i = 0; i < 8; ++i) {
                int g = (wv - 4) * 8 + i;
                int b = g >> 2, dq = g & 3;
                gload_lds16(Vt + (size_t)(((b << 3) + h) * 64 + dq * 16 + (lane & 15)) * 1024 +
                                k0s + (lane >> 4) * 8,
                            &Vl[buf][b * 2048 + dq * 512]);
            }
        }
    };

    const int kbase = kc * 256;
    stage(kbase, 0);
    __syncthreads();  // drains vmcnt: buffer 0 ready

    int buf = 0;
    for (int it = 0; it < 8; ++it) {
        if (it < 7) stage(kbase + (it + 1) * 32, buf ^ 1);  // prefetch under compute

        const USHORT* Kb = Kl[buf];
        const USHORT* Vb = Vl[buf];

        // ---- scores: sacc[b][nt] covers (16q x 32key), accumulate over ks ----
        f32x4 sacc[8][2];
#pragma unroll
        for (int b = 0; b < 8; ++b) { sacc[b][0] = fz4(); sacc[b][1] = fz4(); }
#pragma unroll
        for (int ks = 0; ks < 2; ++ks)
#pragma unroll
            for (int nt = 0; nt < 2; ++nt) {
                bf16x8 kf[8];
#pragma unroll
                for (int b = 0; b < 8; ++b)
                    kf[b] = ldbf8(&Kb[(b * 2 + ks) * 1024 + nt * 512 + lane * 8]);
#pragma unroll
                for (int b = 0; b < 8; ++b)
                    sacc[b][nt] = mfma16(qf[b][ks], kf[b], sacc[b][nt]);
            }

        // ---- softmax over batch axis (per-lane), normalize sacc IN PLACE ----
        // scores*scale ~ N(0,0.2^2): exp2 arg |x| < 2 even at 8 sigma.
#pragma unroll
        for (int nt = 0; nt < 2; ++nt)
#pragma unroll
            for (int r = 0; r < 4; ++r) {
                float e[8];
                float Z = 0.f;
#pragma unroll
                for (int b = 0; b < 8; ++b) {
                    // 0.125 (1/sqrt(64)) * log2(e)
                    e[b] = __builtin_amdgcn_exp2f(sacc[b][nt][r] * 0.1803368801f);
                    Z += e[b];
                }
                float inv = __builtin_amdgcn_rcpf(Z);
#pragma unroll
                for (int b = 0; b < 8; ++b)
                    sacc[b][nt][r] = e[b] * inv;
            }

        // ---- PV per batch: stage attn tile via wave-private LDS, then MFMA ----
#pragma unroll
        for (int b = 0; b < 8; ++b) {
            // C-layout (col=key=l16, row=q=quad*4+r) -> A-layout (m=q=l16,
            // k=key=quad*8+j) through the wave-private [16][40] tile
#pragma unroll
            for (int nt = 0; nt < 2; ++nt)
#pragma unroll
                for (int r = 0; r < 4; ++r)
                    aw[quad * 4 + r][nt * 16 + l16] = f2bf(sacc[b][nt][r]);
            lds_fence();  // ds_write -> ds_read (wave-private)

            bf16x8 af = *(const bf16x8*)&aw[l16][quad * 8];
            bf16x8 vf[4];
#pragma unroll
            for (int nt = 0; nt < 4; ++nt)
                vf[nt] = ldbf8(&Vb[b * 2048 + nt * 512 + lane * 8]);
#pragma unroll
            for (int nt = 0; nt < 4; ++nt)
                oacc[b][nt] = mfma16(af, vf[nt], oacc[b][nt]);
            lds_fence();  // WAR: reads drained before next b overwrites tile
        }

        __syncthreads();  // drains vmcnt: prefetched buffer ready; LDS reads done
        buf ^= 1;
    }

    // ---- epilogue: full-128B-line stores via per-wave LDS transpose ----
    // After the loop's final __syncthreads all staging traffic is done -> the
    // Kl region is dead; reuse it as 8 wave-private [16][72] USHORT tiles
    // (72 stride: 144B rows, 16B-aligned since 144 = 9*16; pad breaks the
    // worst bank aliasing). Per b: write C-layout -> fence -> each lane reads
    // one u16x8 (row = half*8 + lane>>3, seg = lane&7) -> one global u16x8
    // store; 8 lanes cover a full 128B-aligned row line.
    USHORT* part = (kc == 0) ? pt0 : (kc == 1) ? pt1 : (kc == 2) ? pt2 : pt3;
    USHORT* ep = ((USHORT*)Kl) + wv * (16 * 72);
#pragma unroll
    for (int b = 0; b < 8; ++b) {
#pragma unroll
        for (int nt = 0; nt < 4; ++nt)
#pragma unroll
            for (int r = 0; r < 4; ++r)
                ep[(quad * 4 + r) * 72 + nt * 16 + l16] = f2bf(oacc[b][nt][r]);
        lds_fence();  // ds_write -> ds_read (wave-private)
#pragma unroll
        for (int half = 0; half < 2; ++half) {
            int row = half * 8 + (lane >> 3);
            int seg = lane & 7;
            u16x8 v = *(const u16x8*)&ep[row * 72 + seg * 8];
            *(u16x8*)(part + (size_t)((b << 10) + q0 + row) * 512 + h * 64 + seg * 8) = v;
        }
        lds_fence();  // WAR: reads drained before next b overwrites tile
    }
}

extern "C" void kernel_launch(void* const* d_in, const int* in_sizes, int n_in,
                              void* d_out, int out_size, void* d_ws, size_t ws_size,
                              hipStream_t stream) {
    const float* X = (const float*)d_in[0];     // (8,1024,512)
    const float* Wqkv = (const float*)d_in[1];  // (512,1536) — only cols 0..639 used
    const float* Wout = (const float*)d_in[2];  // (512,512)
    float* out = (float*)d_out;                 // (8,1024,512) fp32

    char* w = (char*)d_ws;
    USHORT* Xb  = (USHORT*)(w);              //  8,388,608 B (reused as parts[0]/CtxB)
    USHORT* Wt1 = (USHORT*)(w + 8388608);    //    655,360 B  (640x512)
    USHORT* Wt3 = (USHORT*)(w + 9043968);    //    524,288 B  (512x512)
    USHORT* P   = (USHORT*)(w + 9568256);    // 10,485,760 B  (8192x640 bf16)
    USHORT* Vt  = (USHORT*)(w + 20054016);   //  8,388,608 B  (8x8x64x1024 bf16)
    USHORT* pt1 = (USHORT*)(w + 28442624);   //  8,388,608 B  partial ctx (kc=1)
    USHORT* pt2 = (USHORT*)(w + 36831232);   //  8,388,608 B  partial ctx (kc=2)
    USHORT* pt3 = (USHORT*)(w + 45219840);   //  8,388,608 B  partial ctx (kc=3) end=53.6MB
    USHORT* pt0 = Xb;                        // Xb dead after GEMM1; also reduce4 output
    USHORT* CtxB = Xb;

    prep_kernel<<<4352, 256, 0, stream>>>(X, Wqkv, Wout, Xb, Wt1, Wt3);
    // P = Xb @ Wqkv[:, :640]
    gemm_bt<true><<<dim3(64, 5), 256, 0, stream>>>(Xb, Wt1, (void*)P, 8192, 640, 512);
    transpose_v<<<dim3(16, 8, 8), 256, 0, stream>>>(P, Vt);
    attn_kernel<<<dim3(8, 8, 4), 512, 0, stream>>>(P, Vt, pt0, pt1, pt2, pt3);
    // CtxB = sum of partials (in-place over pt0, fp32 accumulation)
    reduce4<<<2048, 256, 0, stream>>>(pt0, pt1, pt2, pt3, CtxB);
    // out = ctx @ W_out
    gemm_bt<false><<<dim3(64, 4), 256, 0, stream>>>(CtxB, Wt3, (void*)out, 8192, 512, 512);
}

// Round 7
// 227.556 us; speedup vs baseline: 1.0503x; 1.0503x over previous
//
#include <hip/hip_runtime.h>

typedef __bf16 bf16x8 __attribute__((ext_vector_type(8)));
typedef float  f32x4  __attribute__((ext_vector_type(4)));
typedef unsigned short u16x8 __attribute__((ext_vector_type(8)));
typedef unsigned short USHORT;

__device__ __forceinline__ USHORT f2bf(float f) {
    unsigned u = __float_as_uint(f);
    u += 0x7fffu + ((u >> 16) & 1u);
    return (USHORT)(u >> 16);
}

__device__ __forceinline__ float bf2f(USHORT v) {
    return __uint_as_float((unsigned)v << 16);
}

__device__ __forceinline__ f32x4 fz4() { f32x4 z = {0.f, 0.f, 0.f, 0.f}; return z; }

__device__ __forceinline__ bf16x8 ldbf8(const USHORT* p) { return *(const bf16x8*)p; }

__device__ __forceinline__ f32x4 mfma16(bf16x8 a, bf16x8 b, f32x4 c) {
    return __builtin_amdgcn_mfma_f32_16x16x32_bf16(a, b, c, 0, 0, 0);
}

// async global->LDS, 16B per lane; LDS dest is wave-uniform base + lane*16
__device__ __forceinline__ void gload_lds16(const void* g, void* s) {
    __builtin_amdgcn_global_load_lds(
        (const __attribute__((address_space(1))) unsigned int*)g,
        (__attribute__((address_space(3))) unsigned int*)s, 16, 0, 0);
}

// per-wave LDS ordering fence (wave-private LDS region). sched_barrier after the
// waitcnt per guide rule #18.
__device__ __forceinline__ void lds_fence() {
    asm volatile("s_waitcnt lgkmcnt(0)" ::: "memory");
    __builtin_amdgcn_sched_barrier(0);
}

// ---------------- merged prep: X fp32->bf16 + both W transposes ----------------
__global__ __launch_bounds__(256) void prep_kernel(const float* __restrict__ X,
                                                   const float* __restrict__ Wqkv,
                                                   const float* __restrict__ Wout,
                                                   USHORT* __restrict__ Xb,
                                                   USHORT* __restrict__ Wt1,
                                                   USHORT* __restrict__ Wt3) {
    int bid = blockIdx.x;
    if (bid < 2048) {
        int base = (bid * 256 + threadIdx.x) * 8;
        float4 a = *(const float4*)(X + base);
        float4 b = *(const float4*)(X + base + 4);
        u16x8 o;
        o[0] = f2bf(a.x); o[1] = f2bf(a.y); o[2] = f2bf(a.z); o[3] = f2bf(a.w);
        o[4] = f2bf(b.x); o[5] = f2bf(b.y); o[6] = f2bf(b.z); o[7] = f2bf(b.w);
        *(u16x8*)(Xb + base) = o;
    } else if (bid < 3328) {
        int t = (bid - 2048) * 256 + threadIdx.x;   // 0..327679 : 640x512
        int k = t & 511, n = t >> 9;
        Wt1[t] = f2bf(Wqkv[(size_t)k * 1536 + n]);
    } else {
        int t = (bid - 3328) * 256 + threadIdx.x;   // 0..262143 : 512x512
        int k = t & 511, n = t >> 9;
        Wt3[t] = f2bf(Wout[(size_t)k * 512 + n]);
    }
}

// ---------------- 4-way partial-ctx reduce: o = bf16(sum fp32(parts)) ----------
// In-place safe with o == a (each thread reads its 8 elems before writing them).
__global__ __launch_bounds__(256) void reduce4(const USHORT* __restrict__ a,
                                               const USHORT* __restrict__ b,
                                               const USHORT* __restrict__ c,
                                               const USHORT* __restrict__ d,
                                               USHORT* __restrict__ o) {
    int base = (blockIdx.x * 256 + threadIdx.x) * 8;
    u16x8 va = *(const u16x8*)(a + base);
    u16x8 vb = *(const u16x8*)(b + base);
    u16x8 vc = *(const u16x8*)(c + base);
    u16x8 vd = *(const u16x8*)(d + base);
    u16x8 out;
#pragma unroll
    for (int j = 0; j < 8; ++j)
        out[j] = f2bf(bf2f(va[j]) + bf2f(vb[j]) + bf2f(vc[j]) + bf2f(vd[j]));
    *(u16x8*)(o + base) = out;
}

// ---------------- m97-style bf16 GEMM: C = A(MxK) * Bt(NxK)^T -------------------
template <bool BF16OUT>
__global__ __launch_bounds__(256) void gemm_bt(const USHORT* __restrict__ A,
                                               const USHORT* __restrict__ Bt,
                                               void* __restrict__ Cv,
                                               int M, int N, int K) {
    __shared__ __align__(16) USHORT Asm[128 * 32];
    __shared__ __align__(16) USHORT Bsm[128 * 32];
    const int tid = threadIdx.x;
    const int wv = tid >> 6, ln = tid & 63;
    const int l16 = ln & 15, quad = ln >> 4;
    const int m0 = blockIdx.x * 128, n0 = blockIdx.y * 128;
    const int wm = (wv >> 1) * 64, wn = (wv & 1) * 64;

    f32x4 acc[4][4];
#pragma unroll
    for (int i = 0; i < 4; ++i)
#pragma unroll
        for (int j = 0; j < 4; ++j) acc[i][j] = fz4();

    const int kTiles = K >> 5;
    for (int kt = 0; kt < kTiles; ++kt) {
        __syncthreads();
#pragma unroll
        for (int i = 0; i < 2; ++i) {
            int cb = wv * 128 + i * 64;
            int c = cb + ln;
            gload_lds16(A + (size_t)(m0 + (c >> 2)) * K + kt * 32 + (c & 3) * 8,
                        &Asm[cb * 8]);
            gload_lds16(Bt + (size_t)(n0 + (c >> 2)) * K + kt * 32 + (c & 3) * 8,
                        &Bsm[cb * 8]);
        }
        __syncthreads();

        bf16x8 af[4], bfr[4];
#pragma unroll
        for (int i = 0; i < 4; ++i)
            af[i] = ldbf8(&Asm[(wm + i * 16 + l16) * 32 + quad * 8]);
#pragma unroll
        for (int j = 0; j < 4; ++j)
            bfr[j] = ldbf8(&Bsm[(wn + j * 16 + l16) * 32 + quad * 8]);
#pragma unroll
        for (int i = 0; i < 4; ++i)
#pragma unroll
            for (int j = 0; j < 4; ++j)
                acc[i][j] = mfma16(af[i], bfr[j], acc[i][j]);
    }

#pragma unroll
    for (int i = 0; i < 4; ++i)
#pragma unroll
        for (int j = 0; j < 4; ++j)
#pragma unroll
            for (int r = 0; r < 4; ++r) {
                size_t row = m0 + wm + i * 16 + quad * 4 + r;
                size_t col = n0 + wn + j * 16 + l16;
                if (BF16OUT)
                    ((USHORT*)Cv)[row * N + col] = f2bf(acc[i][j][r]);
                else
                    ((float*)Cv)[row * N + col] = acc[i][j][r];
            }
}

// ---------------- V transpose: Vt[((b*8+h)*64+d)*1024+k] = P[(b*1024+k)*640+(h+2)*64+d]
__global__ __launch_bounds__(256) void transpose_v(const USHORT* __restrict__ P,
                                                   USHORT* __restrict__ Vt) {
    __shared__ __align__(16) USHORT T[64][72];
    const int t = threadIdx.x;
    const int k0 = blockIdx.x * 64;
    const int hh = blockIdx.y;
    const int b = blockIdx.z;
#pragma unroll
    for (int i = 0; i < 2; ++i) {
        int c = i * 256 + t;
        int kk = c >> 3, d8 = (c & 7) * 8;
        u16x8 v = *(const u16x8*)(P + (size_t)((b << 10) + k0 + kk) * 640 +
                                  (hh + 2) * 64 + d8);
        *(u16x8*)&T[kk][d8] = v;
    }
    __syncthreads();
#pragma unroll
    for (int i = 0; i < 2; ++i) {
        int d = (t >> 3) + i * 32;
        int kk0 = (t & 7) * 8;
        u16x8 v;
#pragma unroll
        for (int j = 0; j < 8; ++j) v[j] = T[kk0 + j][d];
        *(u16x8*)(Vt + (size_t)(((b << 3) + hh) * 64 + d) * 1024 + k0 + kk0) = v;
    }
}

// ---------------- fused attention v8 -------------------------------------------
// r6 PMC: WRITE 168MB vs 33.5MB payload + VGPR stuck at 128 -> ~50-60 regs/lane
// of scratch SPILL traffic (demand ~310 vs 256/wave cap at 8 waves/CU). v8
// restructures to fit 256 regs with ZERO spills:
//   (1) softmax writes normalized bf16 DIRECTLY into per-(wave,b) LDS tiles ->
//       sacc dies per nt-block (32 live, not 64 across the PV loop).
//   (2) nt-blocked scores: keys 0-15 fully processed (MFMA+softmax+store), then
//       keys 16-31. Peak live: oacc 128 (AGPR) + qf 64 + sacc 32 + kf/temps ~30.
//   (3) tiles are stored in MFMA A-FRAGMENT ORDER: 16B chunk c=((key>>3)<<4)|q
//       holds lane c's A-operand -> PV read = base + lane*16 (conflict-free).
//       Scatter WRITES are de-conflicted by the XOR swizzle p = c ^ ((c>>3)&7)
//       (spreads the 8 chunks of a store instr over all 8 bank-quads); read side
//       applies the same XOR (lane-constant, precomputed).
//   (4) LDS refit: Kl 32 + Vl 32 + tiles 64 = 128KB -> double-buffer dropped
//       (stage-drain exposed ~0.2-0.5us/it, tolerable once staging hits L2).
//   (5) XCD-grouped 1-D grid: g=bid&31 -> (h,kc), qb=bid>>5. All 8 qb-siblings
//       of a group share bid%8 -> same XCD (round-robin heuristic) -> K/V
//       staging hits that XCD's L2 (unique K/V per group 512KB << 4MB).
__global__ __launch_bounds__(512, 2) void attn_kernel(const USHORT* __restrict__ P,
                                                      const USHORT* __restrict__ Vt,
                                                      USHORT* __restrict__ pt0,
                                                      USHORT* __restrict__ pt1,
                                                      USHORT* __restrict__ pt2,
                                                      USHORT* __restrict__ pt3) {
    const int bid = blockIdx.x;
    const int g = bid & 31;                       // group (h,kc): fixed bid%8 -> one XCD
    const int h = g >> 2;
    const int kc = g & 3;
    const int qb = bid >> 5;
    const int tid = threadIdx.x;
    const int wv = tid >> 6;                      // 0..7
    const int lane = tid & 63;
    const int l16 = lane & 15, quad = lane >> 4;
    const int q0 = qb * 128 + wv * 16;

    // Kl chunk map per (b,ks) 2KB region: chunk = half*64+s holds (key=half*16+(s&15), piece=s>>4)
    // Vl chunk map per (b)    4KB region: chunk = dq*32+s    holds (d=dq*16+(s&15),  piece=s>>4)
    __shared__ __align__(16) USHORT Kl[16384];    // 32KB (epilogue scratch after loop)
    __shared__ __align__(16) USHORT Vl[16384];    // 32KB
    __shared__ __align__(16) USHORT alds[32768];  // 64KB: 8 waves x 8 b x 1KB A-frag tiles

    // per-lane swizzle constants for the attn tiles
    const int hi = l16 >> 3;
    const int cq = quad * 4 + (hi << 4);          // c = cq | r | (nt<<5)
    const int xq = (quad >> 1) | (hi << 1);       // x = xq | (nt<<2) == (c>>3)&7
    const int boff = (l16 & 7) * 2;               // byte within chunk (= j*2)
    const int rdoff = (lane ^ ((lane >> 3) & 7)) << 4;  // PV read: physical chunk of logical lane
    USHORT* mytiles = &alds[(wv * 8) * 512];      // 8 tiles x 512 USHORT

    // Q fragments: A[m=l16 (q-row)][k=ks*32+quad*8+j]  (64 VGPR, held all kernel)
    bf16x8 qf[8][2];
#pragma unroll
    for (int b = 0; b < 8; ++b)
#pragma unroll
        for (int ks = 0; ks < 2; ++ks)
            qf[b][ks] = ldbf8(P + (size_t)((b << 10) + q0 + l16) * 640 + h * 64 +
                              ks * 32 + quad * 8);

    f32x4 oacc[8][4];
#pragma unroll
    for (int b = 0; b < 8; ++b)
#pragma unroll
        for (int nt = 0; nt < 4; ++nt) oacc[b][nt] = fz4();

    const int kbase = kc * 256;
    for (int it = 0; it < 8; ++it) {
        const int k0 = kbase + it * 32;

        __syncthreads();  // prev it's Kl/Vl reads done; safe to overwrite
        // ---- stage K,V for THIS it: 64 gload_lds (8/wave); wv<4 -> K else V ----
        if (wv < 4) {
#pragma unroll
            for (int i = 0; i < 8; ++i) {
                int gg = wv * 8 + i;
                int b = gg >> 2, ks = (gg >> 1) & 1, half = gg & 1;
                gload_lds16(P + (size_t)((b << 10) + k0 + half * 16 + (lane & 15)) * 640 +
                                (h + 1) * 64 + ks * 32 + (lane >> 4) * 8,
                            &Kl[(b * 2 + ks) * 1024 + half * 512]);
            }
        } else {
#pragma unroll
            for (int i = 0; i < 8; ++i) {
                int gg = (wv - 4) * 8 + i;
                int b = gg >> 2, dq = gg & 3;
                gload_lds16(Vt + (size_t)(((b << 3) + h) * 64 + dq * 16 + (lane & 15)) * 1024 +
                                k0 + (lane >> 4) * 8,
                            &Vl[b * 2048 + dq * 512]);
            }
        }
        __syncthreads();  // drains vmcnt: staged K/V visible to all waves

        // ---- nt-blocked scores + softmax + tile store (sacc: only 32 live) ----
#pragma unroll
        for (int nt = 0; nt < 2; ++nt) {
            f32x4 sacc[8];
#pragma unroll
            for (int b = 0; b < 8; ++b) sacc[b] = fz4();
#pragma unroll
            for (int ks = 0; ks < 2; ++ks) {
                bf16x8 kf[8];
#pragma unroll
                for (int b = 0; b < 8; ++b)
                    kf[b] = ldbf8(&Kl[(b * 2 + ks) * 1024 + nt * 512 + lane * 8]);
#pragma unroll
                for (int b = 0; b < 8; ++b)
                    sacc[b] = mfma16(qf[b][ks], kf[b], sacc[b]);
            }
            // softmax over batch axis (per-lane), write normalized bf16 to tiles.
            // scores*scale ~ N(0,0.2^2): exp2 arg |x| < 2 even at 8 sigma.
#pragma unroll
            for (int r = 0; r < 4; ++r) {
                float e[8];
                float Z = 0.f;
#pragma unroll
                for (int b = 0; b < 8; ++b) {
                    // 0.125 (1/sqrt(64)) * log2(e)
                    e[b] = __builtin_amdgcn_exp2f(sacc[b][r] * 0.1803368801f);
                    Z += e[b];
                }
                float inv = __builtin_amdgcn_rcpf(Z);
                int c = cq | r | (nt << 5);
                int x = xq | (nt << 2);
                int off = (((c ^ x) << 4) | boff);
#pragma unroll
                for (int b = 0; b < 8; ++b)
                    *(USHORT*)((char*)(mytiles + b * 512) + off) = f2bf(e[b] * inv);
            }
        }
        lds_fence();  // own-wave tile writes -> PV reads

        // ---- PV: A = attn tile (A-frag order, swizzled), B = V from LDS ----
#pragma unroll
        for (int b = 0; b < 8; ++b) {
            bf16x8 af = *(const bf16x8*)((const char*)(mytiles + b * 512) + rdoff);
            bf16x8 vf[4];
#pragma unroll
            for (int nt = 0; nt < 4; ++nt)
                vf[nt] = ldbf8(&Vl[b * 2048 + nt * 512 + lane * 8]);
#pragma unroll
            for (int nt = 0; nt < 4; ++nt)
                oacc[b][nt] = mfma16(af, vf[nt], oacc[b][nt]);
        }
        // next it's top __syncthreads orders these reads vs. the next stage/writes
    }

    // ---- epilogue: full-128B-line stores via per-wave LDS transpose ----
    __syncthreads();  // all k-loop LDS traffic done; Kl region is dead scratch
    USHORT* part = (kc == 0) ? pt0 : (kc == 1) ? pt1 : (kc == 2) ? pt2 : pt3;
    USHORT* ep = ((USHORT*)Kl) + wv * (16 * 72);  // 8 x 2.25KB <= 32KB
#pragma unroll
    for (int b = 0; b < 8; ++b) {
#pragma unroll
        for (int nt = 0; nt < 4; ++nt)
#pragma unroll
            for (int r = 0; r < 4; ++r)
                ep[(quad * 4 + r) * 72 + nt * 16 + l16] = f2bf(oacc[b][nt][r]);
        lds_fence();  // ds_write -> ds_read (wave-private)
#pragma unroll
        for (int half = 0; half < 2; ++half) {
            int row = half * 8 + (lane >> 3);
            int seg = lane & 7;
            u16x8 v = *(const u16x8*)&ep[row * 72 + seg * 8];
            *(u16x8*)(part + (size_t)((b << 10) + q0 + row) * 512 + h * 64 + seg * 8) = v;
        }
        lds_fence();  // WAR: reads drained before next b overwrites tile
    }
}

extern "C" void kernel_launch(void* const* d_in, const int* in_sizes, int n_in,
                              void* d_out, int out_size, void* d_ws, size_t ws_size,
                              hipStream_t stream) {
    const float* X = (const float*)d_in[0];     // (8,1024,512)
    const float* Wqkv = (const float*)d_in[1];  // (512,1536) — only cols 0..639 used
    const float* Wout = (const float*)d_in[2];  // (512,512)
    float* out = (float*)d_out;                 // (8,1024,512) fp32

    char* w = (char*)d_ws;
    USHORT* Xb  = (USHORT*)(w);              //  8,388,608 B (reused as parts[0]/CtxB)
    USHORT* Wt1 = (USHORT*)(w + 8388608);    //    655,360 B  (640x512)
    USHORT* Wt3 = (USHORT*)(w + 9043968);    //    524,288 B  (512x512)
    USHORT* P   = (USHORT*)(w + 9568256);    // 10,485,760 B  (8192x640 bf16)
    USHORT* Vt  = (USHORT*)(w + 20054016);   //  8,388,608 B  (8x8x64x1024 bf16)
    USHORT* pt1 = (USHORT*)(w + 28442624);   //  8,388,608 B  partial ctx (kc=1)
    USHORT* pt2 = (USHORT*)(w + 36831232);   //  8,388,608 B  partial ctx (kc=2)
    USHORT* pt3 = (USHORT*)(w + 45219840);   //  8,388,608 B  partial ctx (kc=3) end=53.6MB
    USHORT* pt0 = Xb;                        // Xb dead after GEMM1; also reduce4 output
    USHORT* CtxB = Xb;

    prep_kernel<<<4352, 256, 0, stream>>>(X, Wqkv, Wout, Xb, Wt1, Wt3);
    // P = Xb @ Wqkv[:, :640]
    gemm_bt<true><<<dim3(64, 5), 256, 0, stream>>>(Xb, Wt1, (void*)P, 8192, 640, 512);
    transpose_v<<<dim3(16, 8, 8), 256, 0, stream>>>(P, Vt);
    attn_kernel<<<256, 512, 0, stream>>>(P, Vt, pt0, pt1, pt2, pt3);
    // CtxB = sum of partials (in-place over pt0, fp32 accumulation)
    reduce4<<<2048, 256, 0, stream>>>(pt0, pt1, pt2, pt3, CtxB);
    // out = ctx @ W_out
    gemm_bt<false><<<dim3(64, 4), 256, 0, stream>>>(CtxB, Wt3, (void*)out, 8192, 512, 512);
}

// Round 9
// 188.371 us; speedup vs baseline: 1.2688x; 1.2080x over previous
//
#include <hip/hip_runtime.h>

typedef __bf16 bf16x8 __attribute__((ext_vector_type(8)));
typedef float  f32x4  __attribute__((ext_vector_type(4)));
typedef unsigned short u16x8 __attribute__((ext_vector_type(8)));
typedef unsigned short USHORT;

__device__ __forceinline__ USHORT f2bf(float f) {
    unsigned u = __float_as_uint(f);
    u += 0x7fffu + ((u >> 16) & 1u);
    return (USHORT)(u >> 16);
}

__device__ __forceinline__ float bf2f(USHORT v) {
    return __uint_as_float((unsigned)v << 16);
}

__device__ __forceinline__ f32x4 fz4() { f32x4 z = {0.f, 0.f, 0.f, 0.f}; return z; }

__device__ __forceinline__ bf16x8 ldbf8(const USHORT* p) { return *(const bf16x8*)p; }

__device__ __forceinline__ f32x4 mfma16(bf16x8 a, bf16x8 b, f32x4 c) {
    return __builtin_amdgcn_mfma_f32_16x16x32_bf16(a, b, c, 0, 0, 0);
}

// async global->LDS, 16B per lane; LDS dest is wave-uniform base + lane*16
__device__ __forceinline__ void gload_lds16(const void* g, void* s) {
    __builtin_amdgcn_global_load_lds(
        (const __attribute__((address_space(1))) unsigned int*)g,
        (__attribute__((address_space(3))) unsigned int*)s, 16, 0, 0);
}

// per-wave LDS ordering fence (wave-private LDS region). sched_barrier after the
// waitcnt per guide rule #18.
__device__ __forceinline__ void lds_fence() {
    asm volatile("s_waitcnt lgkmcnt(0)" ::: "memory");
    __builtin_amdgcn_sched_barrier(0);
}

// ---------------- merged prep: X fp32->bf16 + both W transposes ----------------
__global__ __launch_bounds__(256) void prep_kernel(const float* __restrict__ X,
                                                   const float* __restrict__ Wqkv,
                                                   const float* __restrict__ Wout,
                                                   USHORT* __restrict__ Xb,
                                                   USHORT* __restrict__ Wt1,
                                                   USHORT* __restrict__ Wt3) {
    int bid = blockIdx.x;
    if (bid < 2048) {
        int base = (bid * 256 + threadIdx.x) * 8;
        float4 a = *(const float4*)(X + base);
        float4 b = *(const float4*)(X + base + 4);
        u16x8 o;
        o[0] = f2bf(a.x); o[1] = f2bf(a.y); o[2] = f2bf(a.z); o[3] = f2bf(a.w);
        o[4] = f2bf(b.x); o[5] = f2bf(b.y); o[6] = f2bf(b.z); o[7] = f2bf(b.w);
        *(u16x8*)(Xb + base) = o;
    } else if (bid < 3328) {
        int t = (bid - 2048) * 256 + threadIdx.x;   // 0..327679 : 640x512
        int k = t & 511, n = t >> 9;
        Wt1[t] = f2bf(Wqkv[(size_t)k * 1536 + n]);
    } else {
        int t = (bid - 3328) * 256 + threadIdx.x;   // 0..262143 : 512x512
        int k = t & 511, n = t >> 9;
        Wt3[t] = f2bf(Wout[(size_t)k * 512 + n]);
    }
}

// ---------------- 2-way partial-ctx reduce: o = bf16(f32(a)+f32(b)) ------------
// In-place safe with o == a (each thread reads its 8 elems before writing them).
__global__ __launch_bounds__(256) void reduce2(const USHORT* __restrict__ a,
                                               const USHORT* __restrict__ b,
                                               USHORT* __restrict__ o) {
    int base = (blockIdx.x * 256 + threadIdx.x) * 8;
    u16x8 va = *(const u16x8*)(a + base);
    u16x8 vb = *(const u16x8*)(b + base);
    u16x8 out;
#pragma unroll
    for (int j = 0; j < 8; ++j)
        out[j] = f2bf(bf2f(va[j]) + bf2f(vb[j]));
    *(u16x8*)(o + base) = out;
}

// ---------------- m97-style bf16 GEMM: C = A(MxK) * Bt(NxK)^T -------------------
template <bool BF16OUT>
__global__ __launch_bounds__(256) void gemm_bt(const USHORT* __restrict__ A,
                                               const USHORT* __restrict__ Bt,
                                               void* __restrict__ Cv,
                                               int M, int N, int K) {
    __shared__ __align__(16) USHORT Asm[128 * 32];
    __shared__ __align__(16) USHORT Bsm[128 * 32];
    const int tid = threadIdx.x;
    const int wv = tid >> 6, ln = tid & 63;
    const int l16 = ln & 15, quad = ln >> 4;
    const int m0 = blockIdx.x * 128, n0 = blockIdx.y * 128;
    const int wm = (wv >> 1) * 64, wn = (wv & 1) * 64;

    f32x4 acc[4][4];
#pragma unroll
    for (int i = 0; i < 4; ++i)
#pragma unroll
        for (int j = 0; j < 4; ++j) acc[i][j] = fz4();

    const int kTiles = K >> 5;
    for (int kt = 0; kt < kTiles; ++kt) {
        __syncthreads();
#pragma unroll
        for (int i = 0; i < 2; ++i) {
            int cb = wv * 128 + i * 64;
            int c = cb + ln;
            gload_lds16(A + (size_t)(m0 + (c >> 2)) * K + kt * 32 + (c & 3) * 8,
                        &Asm[cb * 8]);
            gload_lds16(Bt + (size_t)(n0 + (c >> 2)) * K + kt * 32 + (c & 3) * 8,
                        &Bsm[cb * 8]);
        }
        __syncthreads();

        bf16x8 af[4], bfr[4];
#pragma unroll
        for (int i = 0; i < 4; ++i)
            af[i] = ldbf8(&Asm[(wm + i * 16 + l16) * 32 + quad * 8]);
#pragma unroll
        for (int j = 0; j < 4; ++j)
            bfr[j] = ldbf8(&Bsm[(wn + j * 16 + l16) * 32 + quad * 8]);
#pragma unroll
        for (int i = 0; i < 4; ++i)
#pragma unroll
            for (int j = 0; j < 4; ++j)
                acc[i][j] = mfma16(af[i], bfr[j], acc[i][j]);
    }

#pragma unroll
    for (int i = 0; i < 4; ++i)
#pragma unroll
        for (int j = 0; j < 4; ++j)
#pragma unroll
            for (int r = 0; r < 4; ++r) {
                size_t row = m0 + wm + i * 16 + quad * 4 + r;
                size_t col = n0 + wn + j * 16 + l16;
                if (BF16OUT)
                    ((USHORT*)Cv)[row * N + col] = f2bf(acc[i][j][r]);
                else
                    ((float*)Cv)[row * N + col] = acc[i][j][r];
            }
}

// ---------------- V transpose: Vt[((b*8+h)*64+d)*1024+k] = P[(b*1024+k)*640+(h+2)*64+d]
__global__ __launch_bounds__(256) void transpose_v(const USHORT* __restrict__ P,
                                                   USHORT* __restrict__ Vt) {
    __shared__ __align__(16) USHORT T[64][72];
    const int t = threadIdx.x;
    const int k0 = blockIdx.x * 64;
    const int hh = blockIdx.y;
    const int b = blockIdx.z;
#pragma unroll
    for (int i = 0; i < 2; ++i) {
        int c = i * 256 + t;
        int kk = c >> 3, d8 = (c & 7) * 8;
        u16x8 v = *(const u16x8*)(P + (size_t)((b << 10) + k0 + kk) * 640 +
                                  (hh + 2) * 64 + d8);
        *(u16x8*)&T[kk][d8] = v;
    }
    __syncthreads();
#pragma unroll
    for (int i = 0; i < 2; ++i) {
        int d = (t >> 3) + i * 32;
        int kk0 = (t & 7) * 8;
        u16x8 v;
#pragma unroll
        for (int j = 0; j < 8; ++j) v[j] = T[kk0 + j][d];
        *(u16x8*)(Vt + (size_t)(((b << 3) + hh) * 64 + d) * 1024 + k0 + kk0) = v;
    }
}

// ---------------- fused attention v9b ------------------------------------------
// r8 lesson: both container failures were the only kernels with LDS > 138KB
// (144KB, 160KB); 138KB ran repeatedly -> hard cap LDS at <=138KB.
// v9b keeps v9's core change -- 4-wave blocks (256 thr), __launch_bounds__(256,1),
// 1 block/CU -> 4 waves/CU -> 512 regs/wave, so the ~340-reg demand fits with
// ~170 slack and the r5-r7 spill traffic (WRITE 185MB vs 33.5MB payload,
// VGPR_Count pinned at 128 = 256-cap overflow) becomes structurally impossible.
// LDS refit to 132KB: Kl[2]+Vl[2] 128KB double-buffer + ONE 1KB swizzled attn
// tile per wave (4KB). Softmax normalizes sacc[8][2] IN PLACE (v5-v7-proven);
// PV writes batch b's tile just-in-time: 8 ds_writes -> fence -> swizzled b128
// read (v8-verified offsets) -> 4 MFMA -> fence.
// Block covers 64 q x 512 keys (kc=2, 16 its); 16 qb-siblings of a (h,kc) group
// share bid%8 -> one XCD -> K/V staging L2-resident (1MB/group, 2 groups/XCD).
__global__ __launch_bounds__(256, 1) void attn_kernel(const USHORT* __restrict__ P,
                                                      const USHORT* __restrict__ Vt,
                                                      USHORT* __restrict__ pt0,
                                                      USHORT* __restrict__ pt1) {
    const int bid = blockIdx.x;
    const int g = bid & 15;                       // group (h,kc)
    const int h = g >> 1;
    const int kc = g & 1;                         // 0..1, 512 keys each
    const int qb = bid >> 4;                      // 0..15, 64 q each
    const int tid = threadIdx.x;
    const int wv = tid >> 6;                      // 0..3
    const int lane = tid & 63;
    const int l16 = lane & 15, quad = lane >> 4;
    const int q0 = qb * 64 + wv * 16;

    // Kl chunk map per (b,ks) 2KB region: chunk = half*64+s holds (key=half*16+(s&15), piece=s>>4)
    // Vl chunk map per (b)    4KB region: chunk = dq*32+s    holds (d=dq*16+(s&15),  piece=s>>4)
    __shared__ __align__(16) USHORT Kl[2][16384];   // 64KB (buf0 = epilogue scratch after loop)
    __shared__ __align__(16) USHORT Vl[2][16384];   // 64KB
    __shared__ __align__(16) USHORT alds[2048];     // 4KB: 4 waves x 1KB swizzled A-frag tile
    USHORT* mytile = &alds[wv * 512];

    // per-lane swizzle constants for the attn tile (v8-verified)
    const int hi = l16 >> 3;
    const int cq = quad * 4 + (hi << 4);          // c = cq | r | (nt<<5)
    const int xq = (quad >> 1) | (hi << 1);       // x = xq | (nt<<2) == (c>>3)&7
    const int boff = (l16 & 7) * 2;               // byte within chunk (= j*2)
    const int rdoff = (lane ^ ((lane >> 3) & 7)) << 4;  // PV read: physical chunk of logical lane

    // Q fragments: A[m=l16 (q-row)][k=ks*32+quad*8+j]  (64 VGPR, held all kernel)
    bf16x8 qf[8][2];
#pragma unroll
    for (int b = 0; b < 8; ++b)
#pragma unroll
        for (int ks = 0; ks < 2; ++ks)
            qf[b][ks] = ldbf8(P + (size_t)((b << 10) + q0 + l16) * 640 + h * 64 +
                              ks * 32 + quad * 8);

    f32x4 oacc[8][4];
#pragma unroll
    for (int b = 0; b < 8; ++b)
#pragma unroll
        for (int nt = 0; nt < 4; ++nt) oacc[b][nt] = fz4();

    // ---- staging: 64 gload_lds per it (16/wave); wv<2 -> K, wv>=2 -> V ----
    auto stage = [&](int k0s, int buf) {
        if (wv < 2) {
#pragma unroll
            for (int i = 0; i < 16; ++i) {
                int gg = wv * 16 + i;             // 0..31
                int b = gg >> 2, ks = (gg >> 1) & 1, half = gg & 1;
                gload_lds16(P + (size_t)((b << 10) + k0s + half * 16 + (lane & 15)) * 640 +
                                (h + 1) * 64 + ks * 32 + (lane >> 4) * 8,
                            &Kl[buf][(b * 2 + ks) * 1024 + half * 512]);
            }
        } else {
#pragma unroll
            for (int i = 0; i < 16; ++i) {
                int gg = (wv - 2) * 16 + i;       // 0..31
                int b = gg >> 2, dq = gg & 3;
                gload_lds16(Vt + (size_t)(((b << 3) + h) * 64 + dq * 16 + (lane & 15)) * 1024 +
                                k0s + (lane >> 4) * 8,
                            &Vl[buf][b * 2048 + dq * 512]);
            }
        }
    };

    const int kbase = kc * 512;
    stage(kbase, 0);
    __syncthreads();  // drains vmcnt: buffer 0 ready

    int buf = 0;
    for (int it = 0; it < 16; ++it) {
        if (it < 15) stage(kbase + (it + 1) * 32, buf ^ 1);  // prefetch under compute

        const USHORT* Kb = Kl[buf];
        const USHORT* Vb = Vl[buf];

        // ---- scores: sacc[b][nt] covers (16q x 32key), accumulate over ks ----
        f32x4 sacc[8][2];
#pragma unroll
        for (int b = 0; b < 8; ++b) { sacc[b][0] = fz4(); sacc[b][1] = fz4(); }
#pragma unroll
        for (int ks = 0; ks < 2; ++ks)
#pragma unroll
            for (int nt = 0; nt < 2; ++nt) {
                bf16x8 kf[8];
#pragma unroll
                for (int b = 0; b < 8; ++b)
                    kf[b] = ldbf8(&Kb[(b * 2 + ks) * 1024 + nt * 512 + lane * 8]);
#pragma unroll
                for (int b = 0; b < 8; ++b)
                    sacc[b][nt] = mfma16(qf[b][ks], kf[b], sacc[b][nt]);
            }

        // ---- softmax over batch axis (per-lane), normalize sacc IN PLACE ----
        // scores*scale ~ N(0,0.2^2): exp2 arg |x| < 2 even at 8 sigma.
#pragma unroll
        for (int nt = 0; nt < 2; ++nt)
#pragma unroll
            for (int r = 0; r < 4; ++r) {
                float e[8];
                float Z = 0.f;
#pragma unroll
                for (int b = 0; b < 8; ++b) {
                    // 0.125 (1/sqrt(64)) * log2(e)
                    e[b] = __builtin_amdgcn_exp2f(sacc[b][nt][r] * 0.1803368801f);
                    Z += e[b];
                }
                float inv = __builtin_amdgcn_rcpf(Z);
#pragma unroll
                for (int b = 0; b < 8; ++b)
                    sacc[b][nt][r] = e[b] * inv;
            }

        // ---- PV per batch: just-in-time swizzled tile, then MFMA ----
#pragma unroll
        for (int b = 0; b < 8; ++b) {
#pragma unroll
            for (int nt = 0; nt < 2; ++nt)
#pragma unroll
                for (int r = 0; r < 4; ++r) {
                    int c = cq | r | (nt << 5);
                    int x = xq | (nt << 2);
                    int off = (((c ^ x) << 4) | boff);
                    *(USHORT*)((char*)mytile + off) = f2bf(sacc[b][nt][r]);
                }
            lds_fence();  // ds_write -> ds_read (wave-private)

            bf16x8 af = *(const bf16x8*)((const char*)mytile + rdoff);
            bf16x8 vf[4];
#pragma unroll
            for (int nt = 0; nt < 4; ++nt)
                vf[nt] = ldbf8(&Vb[b * 2048 + nt * 512 + lane * 8]);
#pragma unroll
            for (int nt = 0; nt < 4; ++nt)
                oacc[b][nt] = mfma16(af, vf[nt], oacc[b][nt]);
            lds_fence();  // WAR: reads drained before next b overwrites tile
        }

        __syncthreads();  // drains vmcnt (prefetch landed) + all LDS reads done
        buf ^= 1;
    }

    // ---- epilogue: full-128B-line stores via per-wave LDS transpose ----
    // loop's final barrier done: all staging/LDS traffic finished -> Kl dead.
    USHORT* part = kc ? pt1 : pt0;
    USHORT* ep = ((USHORT*)Kl) + wv * (16 * 72);  // 4 x 2.25KB <= 64KB
#pragma unroll
    for (int b = 0; b < 8; ++b) {
#pragma unroll
        for (int nt = 0; nt < 4; ++nt)
#pragma unroll
            for (int r = 0; r < 4; ++r)
                ep[(quad * 4 + r) * 72 + nt * 16 + l16] = f2bf(oacc[b][nt][r]);
        lds_fence();  // ds_write -> ds_read (wave-private)
#pragma unroll
        for (int half = 0; half < 2; ++half) {
            int row = half * 8 + (lane >> 3);
            int seg = lane & 7;
            u16x8 v = *(const u16x8*)&ep[row * 72 + seg * 8];
            *(u16x8*)(part + (size_t)((b << 10) + q0 + row) * 512 + h * 64 + seg * 8) = v;
        }
        lds_fence();  // WAR: reads drained before next b overwrites tile
    }
}

extern "C" void kernel_launch(void* const* d_in, const int* in_sizes, int n_in,
                              void* d_out, int out_size, void* d_ws, size_t ws_size,
                              hipStream_t stream) {
    const float* X = (const float*)d_in[0];     // (8,1024,512)
    const float* Wqkv = (const float*)d_in[1];  // (512,1536) — only cols 0..639 used
    const float* Wout = (const float*)d_in[2];  // (512,512)
    float* out = (float*)d_out;                 // (8,1024,512) fp32

    char* w = (char*)d_ws;
    USHORT* Xb  = (USHORT*)(w);              //  8,388,608 B (reused as parts[0]/CtxB)
    USHORT* Wt1 = (USHORT*)(w + 8388608);    //    655,360 B  (640x512)
    USHORT* Wt3 = (USHORT*)(w + 9043968);    //    524,288 B  (512x512)
    USHORT* P   = (USHORT*)(w + 9568256);    // 10,485,760 B  (8192x640 bf16)
    USHORT* Vt  = (USHORT*)(w + 20054016);   //  8,388,608 B  (8x8x64x1024 bf16)
    USHORT* pt1 = (USHORT*)(w + 28442624);   //  8,388,608 B  partial ctx (kc=1)
    USHORT* pt0 = Xb;                        // Xb dead after GEMM1; also reduce2 output
    USHORT* CtxB = Xb;

    prep_kernel<<<4352, 256, 0, stream>>>(X, Wqkv, Wout, Xb, Wt1, Wt3);
    // P = Xb @ Wqkv[:, :640]
    gemm_bt<true><<<dim3(64, 5), 256, 0, stream>>>(Xb, Wt1, (void*)P, 8192, 640, 512);
    transpose_v<<<dim3(16, 8, 8), 256, 0, stream>>>(P, Vt);
    attn_kernel<<<256, 256, 0, stream>>>(P, Vt, pt0, pt1);
    // CtxB = pt0 + pt1 (in-place over pt0, fp32 accumulation)
    reduce2<<<2048, 256, 0, stream>>>(pt0, pt1, CtxB);
    // out = ctx @ W_out
    gemm_bt<false><<<dim3(64, 4), 256, 0, stream>>>(CtxB, Wt3, (void*)out, 8192, 512, 512);
}

// Round 10
// 175.734 us; speedup vs baseline: 1.3600x; 1.0719x over previous
//
#include <hip/hip_runtime.h>

typedef __bf16 bf16x8 __attribute__((ext_vector_type(8)));
typedef float  f32x4  __attribute__((ext_vector_type(4)));
typedef unsigned short u16x8 __attribute__((ext_vector_type(8)));
typedef unsigned short USHORT;
typedef unsigned int   u32;

__device__ __forceinline__ USHORT f2bf(float f) {
    unsigned u = __float_as_uint(f);
    u += 0x7fffu + ((u >> 16) & 1u);
    return (USHORT)(u >> 16);
}

__device__ __forceinline__ float bf2f(USHORT v) {
    return __uint_as_float((unsigned)v << 16);
}

__device__ __forceinline__ u32 packbf(float lo, float hi) {
    return (u32)f2bf(lo) | ((u32)f2bf(hi) << 16);
}

__device__ __forceinline__ f32x4 fz4() { f32x4 z = {0.f, 0.f, 0.f, 0.f}; return z; }

__device__ __forceinline__ bf16x8 ldbf8(const USHORT* p) { return *(const bf16x8*)p; }

__device__ __forceinline__ f32x4 mfma16(bf16x8 a, bf16x8 b, f32x4 c) {
    return __builtin_amdgcn_mfma_f32_16x16x32_bf16(a, b, c, 0, 0, 0);
}

// async global->LDS, 16B per lane; LDS dest is wave-uniform base + lane*16
__device__ __forceinline__ void gload_lds16(const void* g, void* s) {
    __builtin_amdgcn_global_load_lds(
        (const __attribute__((address_space(1))) unsigned int*)g,
        (__attribute__((address_space(3))) unsigned int*)s, 16, 0, 0);
}

// per-wave LDS ordering fence (epilogue only). sched_barrier per guide rule #18.
__device__ __forceinline__ void lds_fence() {
    asm volatile("s_waitcnt lgkmcnt(0)" ::: "memory");
    __builtin_amdgcn_sched_barrier(0);
}

// ---------------- merged prep: X fp32->bf16 + both W transposes ----------------
__global__ __launch_bounds__(256) void prep_kernel(const float* __restrict__ X,
                                                   const float* __restrict__ Wqkv,
                                                   const float* __restrict__ Wout,
                                                   USHORT* __restrict__ Xb,
                                                   USHORT* __restrict__ Wt1,
                                                   USHORT* __restrict__ Wt3) {
    int bid = blockIdx.x;
    if (bid < 2048) {
        int base = (bid * 256 + threadIdx.x) * 8;
        float4 a = *(const float4*)(X + base);
        float4 b = *(const float4*)(X + base + 4);
        u16x8 o;
        o[0] = f2bf(a.x); o[1] = f2bf(a.y); o[2] = f2bf(a.z); o[3] = f2bf(a.w);
        o[4] = f2bf(b.x); o[5] = f2bf(b.y); o[6] = f2bf(b.z); o[7] = f2bf(b.w);
        *(u16x8*)(Xb + base) = o;
    } else if (bid < 3328) {
        int t = (bid - 2048) * 256 + threadIdx.x;   // 0..327679 : 640x512
        int k = t & 511, n = t >> 9;
        Wt1[t] = f2bf(Wqkv[(size_t)k * 1536 + n]);
    } else {
        int t = (bid - 3328) * 256 + threadIdx.x;   // 0..262143 : 512x512
        int k = t & 511, n = t >> 9;
        Wt3[t] = f2bf(Wout[(size_t)k * 512 + n]);
    }
}

// ---------------- 2-way partial-ctx reduce: o = bf16(f32(a)+f32(b)) ------------
// In-place safe with o == a (each thread reads its 8 elems before writing them).
__global__ __launch_bounds__(256) void reduce2(const USHORT* __restrict__ a,
                                               const USHORT* __restrict__ b,
                                               USHORT* __restrict__ o) {
    int base = (blockIdx.x * 256 + threadIdx.x) * 8;
    u16x8 va = *(const u16x8*)(a + base);
    u16x8 vb = *(const u16x8*)(b + base);
    u16x8 out;
#pragma unroll
    for (int j = 0; j < 8; ++j)
        out[j] = f2bf(bf2f(va[j]) + bf2f(vb[j]));
    *(u16x8*)(o + base) = out;
}

// ---------------- m97-style bf16 GEMM: C = A(MxK) * Bt(NxK)^T -------------------
template <bool BF16OUT>
__global__ __launch_bounds__(256) void gemm_bt(const USHORT* __restrict__ A,
                                               const USHORT* __restrict__ Bt,
                                               void* __restrict__ Cv,
                                               int M, int N, int K) {
    __shared__ __align__(16) USHORT Asm[128 * 32];
    __shared__ __align__(16) USHORT Bsm[128 * 32];
    const int tid = threadIdx.x;
    const int wv = tid >> 6, ln = tid & 63;
    const int l16 = ln & 15, quad = ln >> 4;
    const int m0 = blockIdx.x * 128, n0 = blockIdx.y * 128;
    const int wm = (wv >> 1) * 64, wn = (wv & 1) * 64;

    f32x4 acc[4][4];
#pragma unroll
    for (int i = 0; i < 4; ++i)
#pragma unroll
        for (int j = 0; j < 4; ++j) acc[i][j] = fz4();

    const int kTiles = K >> 5;
    for (int kt = 0; kt < kTiles; ++kt) {
        __syncthreads();
#pragma unroll
        for (int i = 0; i < 2; ++i) {
            int cb = wv * 128 + i * 64;
            int c = cb + ln;
            gload_lds16(A + (size_t)(m0 + (c >> 2)) * K + kt * 32 + (c & 3) * 8,
                        &Asm[cb * 8]);
            gload_lds16(Bt + (size_t)(n0 + (c >> 2)) * K + kt * 32 + (c & 3) * 8,
                        &Bsm[cb * 8]);
        }
        __syncthreads();

        bf16x8 af[4], bfr[4];
#pragma unroll
        for (int i = 0; i < 4; ++i)
            af[i] = ldbf8(&Asm[(wm + i * 16 + l16) * 32 + quad * 8]);
#pragma unroll
        for (int j = 0; j < 4; ++j)
            bfr[j] = ldbf8(&Bsm[(wn + j * 16 + l16) * 32 + quad * 8]);
#pragma unroll
        for (int i = 0; i < 4; ++i)
#pragma unroll
            for (int j = 0; j < 4; ++j)
                acc[i][j] = mfma16(af[i], bfr[j], acc[i][j]);
    }

#pragma unroll
    for (int i = 0; i < 4; ++i)
#pragma unroll
        for (int j = 0; j < 4; ++j)
#pragma unroll
            for (int r = 0; r < 4; ++r) {
                size_t row = m0 + wm + i * 16 + quad * 4 + r;
                size_t col = n0 + wn + j * 16 + l16;
                if (BF16OUT)
                    ((USHORT*)Cv)[row * N + col] = f2bf(acc[i][j][r]);
                else
                    ((float*)Cv)[row * N + col] = acc[i][j][r];
            }
}

// ---------------- V transpose: Vt[((b*8+h)*64+d)*1024+k] = P[(b*1024+k)*640+(h+2)*64+d]
__global__ __launch_bounds__(256) void transpose_v(const USHORT* __restrict__ P,
                                                   USHORT* __restrict__ Vt) {
    __shared__ __align__(16) USHORT T[64][72];
    const int t = threadIdx.x;
    const int k0 = blockIdx.x * 64;
    const int hh = blockIdx.y;
    const int b = blockIdx.z;
#pragma unroll
    for (int i = 0; i < 2; ++i) {
        int c = i * 256 + t;
        int kk = c >> 3, d8 = (c & 7) * 8;
        u16x8 v = *(const u16x8*)(P + (size_t)((b << 10) + k0 + kk) * 640 +
                                  (hh + 2) * 64 + d8);
        *(u16x8*)&T[kk][d8] = v;
    }
    __syncthreads();
#pragma unroll
    for (int i = 0; i < 2; ++i) {
        int d = (t >> 3) + i * 32;
        int kk0 = (t & 7) * 8;
        u16x8 v;
#pragma unroll
        for (int j = 0; j < 8; ++j) v[j] = T[kk0 + j][d];
        *(u16x8*)(Vt + (size_t)(((b << 3) + hh) * 64 + d) * 1024 + k0 + kk0) = v;
    }
}

// ---------------- fused attention v10 ------------------------------------------
// r9 PMC: traffic solved (33.7MB total, VGPR 224 = no spills) but 1 wave/SIMD
// latency-bound: MfmaUtil 8.4 / VALUBusy 28.8 / ~60% stall. Dominant serial
// structure was PV's per-batch LDS round-trip with 2 sched_barrier(0) fences
// (16 hard serialization points x ~120cy LDS latency per it).
// v10: SWAPPED-OPERAND scores + ds_permute PV (T12 mechanism, 16x16 variant):
//   scores = mfma(K, Q)  -> P^T: lane=q(l16), row=key(quad*4+r); A/B register
//   layouts are identical for 16x16x32 so kf/qf registers are unchanged.
//   Softmax over batch axis: untouched (per-lane, per-register).
//   PV: out^T = mfma(A=V, B=P^T). B fragment (lane=q, k=key=quad*8+j) built
//   from score regs by 4 ds_permute pushes per batch (injective per op;
//   verified element-wise for dest lanes 8 and 40):
//     op0/1: even-quad lanes push nt0 -> Q=(quad>>1);  odd push nt1 -> Q=2+(quad>>1)
//     op2/3: even-quad lanes push nt1 -> Q=2+(quad>>1); odd push nt0 -> Q=(quad>>1)
//   receive order differs for lanes quad>=2 -> 4 cndmask swap. No LDS memory,
//   no fences, pure dataflow -> compiler pipelines across all 8 batches.
// oacc is now TRANSPOSED (lane=q, row=d): epilogue LDS write index adapted.
// alds eliminated -> LDS 128KB (under the 138KB container cap).
__global__ __launch_bounds__(256, 1) void attn_kernel(const USHORT* __restrict__ P,
                                                      const USHORT* __restrict__ Vt,
                                                      USHORT* __restrict__ pt0,
                                                      USHORT* __restrict__ pt1) {
    const int bid = blockIdx.x;
    const int g = bid & 15;                       // group (h,kc)
    const int h = g >> 1;
    const int kc = g & 1;                         // 0..1, 512 keys each
    const int qb = bid >> 4;                      // 0..15, 64 q each
    const int tid = threadIdx.x;
    const int wv = tid >> 6;                      // 0..3
    const int lane = tid & 63;
    const int l16 = lane & 15, quad = lane >> 4;
    const int q0 = qb * 64 + wv * 16;

    // Kl chunk map per (b,ks) 2KB region: chunk = half*64+s holds (key=half*16+(s&15), piece=s>>4)
    // Vl chunk map per (b)    4KB region: chunk = dq*32+s    holds (d=dq*16+(s&15),  piece=s>>4)
    __shared__ __align__(16) USHORT Kl[2][16384];   // 64KB (buf0 = epilogue scratch after loop)
    __shared__ __align__(16) USHORT Vl[2][16384];   // 64KB

    // ds_permute dest byte-indices (dest_lane*4), per-lane constants
    const int qhalf = quad >> 1;                  // 0,0,1,1
    const bool qodd = (quad & 1) != 0;
    const bool qhi  = quad >= 2;
    const int idx01 = ((qodd ? (2 + qhalf) : qhalf) * 16 + l16) * 4;
    const int idx23 = ((qodd ? qhalf : (2 + qhalf)) * 16 + l16) * 4;

    // Q fragments: B-layout [n=l16 (q-row)][k=ks*32+quad*8+j] (64 VGPR, held all kernel)
    bf16x8 qf[8][2];
#pragma unroll
    for (int b = 0; b < 8; ++b)
#pragma unroll
        for (int ks = 0; ks < 2; ++ks)
            qf[b][ks] = ldbf8(P + (size_t)((b << 10) + q0 + l16) * 640 + h * 64 +
                              ks * 32 + quad * 8);

    // oacc TRANSPOSED: oacc[b][nt][r] = out[q=l16][d = nt*16 + quad*4 + r]
    f32x4 oacc[8][4];
#pragma unroll
    for (int b = 0; b < 8; ++b)
#pragma unroll
        for (int nt = 0; nt < 4; ++nt) oacc[b][nt] = fz4();

    // ---- staging: 64 gload_lds per it (16/wave); wv<2 -> K, wv>=2 -> V ----
    auto stage = [&](int k0s, int buf) {
        if (wv < 2) {
#pragma unroll
            for (int i = 0; i < 16; ++i) {
                int gg = wv * 16 + i;             // 0..31
                int b = gg >> 2, ks = (gg >> 1) & 1, half = gg & 1;
                gload_lds16(P + (size_t)((b << 10) + k0s + half * 16 + (lane & 15)) * 640 +
                                (h + 1) * 64 + ks * 32 + (lane >> 4) * 8,
                            &Kl[buf][(b * 2 + ks) * 1024 + half * 512]);
            }
        } else {
#pragma unroll
            for (int i = 0; i < 16; ++i) {
                int gg = (wv - 2) * 16 + i;       // 0..31
                int b = gg >> 2, dq = gg & 3;
                gload_lds16(Vt + (size_t)(((b << 3) + h) * 64 + dq * 16 + (lane & 15)) * 1024 +
                                k0s + (lane >> 4) * 8,
                            &Vl[buf][b * 2048 + dq * 512]);
            }
        }
    };

    const int kbase = kc * 512;
    stage(kbase, 0);
    __syncthreads();  // drains vmcnt: buffer 0 ready

    int buf = 0;
    for (int it = 0; it < 16; ++it) {
        if (it < 15) stage(kbase + (it + 1) * 32, buf ^ 1);  // prefetch under compute

        const USHORT* Kb = Kl[buf];
        const USHORT* Vb = Vl[buf];

        // ---- SWAPPED scores: sacc[b][nt] = P^T tile (lane=q, row=key) ----
        // kf as A: m=key=l16, k=dh=quad*8+j (same register content as before).
        f32x4 sacc[8][2];
#pragma unroll
        for (int b = 0; b < 8; ++b) { sacc[b][0] = fz4(); sacc[b][1] = fz4(); }
#pragma unroll
        for (int ks = 0; ks < 2; ++ks)
#pragma unroll
            for (int nt = 0; nt < 2; ++nt) {
                bf16x8 kf[8];
#pragma unroll
                for (int b = 0; b < 8; ++b)
                    kf[b] = ldbf8(&Kb[(b * 2 + ks) * 1024 + nt * 512 + lane * 8]);
#pragma unroll
                for (int b = 0; b < 8; ++b)
                    sacc[b][nt] = mfma16(kf[b], qf[b][ks], sacc[b][nt]);
            }

        // ---- softmax over batch axis (per-lane), normalize sacc IN PLACE ----
        // Identical code to v9b; (q,key) meaning per lane changed, math didn't.
#pragma unroll
        for (int nt = 0; nt < 2; ++nt)
#pragma unroll
            for (int r = 0; r < 4; ++r) {
                float e[8];
                float Z = 0.f;
#pragma unroll
                for (int b = 0; b < 8; ++b) {
                    // 0.125 (1/sqrt(64)) * log2(e)
                    e[b] = __builtin_amdgcn_exp2f(sacc[b][nt][r] * 0.1803368801f);
                    Z += e[b];
                }
                float inv = __builtin_amdgcn_rcpf(Z);
#pragma unroll
                for (int b = 0; b < 8; ++b)
                    sacc[b][nt][r] = e[b] * inv;
            }

        // ---- PV via ds_permute (no LDS memory, no fences) ----
#pragma unroll
        for (int b = 0; b < 8; ++b) {
            // pack this lane's 8 P^T values (q=l16, keys nt*16+quad*4+r) to bf16
            u32 w00 = packbf(sacc[b][0][0], sacc[b][0][1]);
            u32 w01 = packbf(sacc[b][0][2], sacc[b][0][3]);
            u32 w10 = packbf(sacc[b][1][0], sacc[b][1][1]);
            u32 w11 = packbf(sacc[b][1][2], sacc[b][1][3]);
            // send-side selects (see header for routing table)
            u32 s0 = qodd ? w10 : w00, s1 = qodd ? w11 : w01;
            u32 s2 = qodd ? w00 : w10, s3 = qodd ? w01 : w11;
            u32 r0 = (u32)__builtin_amdgcn_ds_permute(idx01, (int)s0);
            u32 r1 = (u32)__builtin_amdgcn_ds_permute(idx01, (int)s1);
            u32 r2 = (u32)__builtin_amdgcn_ds_permute(idx23, (int)s2);
            u32 r3 = (u32)__builtin_amdgcn_ds_permute(idx23, (int)s3);
            // receive-side order: lanes quad<2 -> [r0,r1,r2,r3]; quad>=2 -> [r2,r3,r0,r1]
            union { u32 u[4]; bf16x8 v; } pu;
            pu.u[0] = qhi ? r2 : r0;
            pu.u[1] = qhi ? r3 : r1;
            pu.u[2] = qhi ? r0 : r2;
            pu.u[3] = qhi ? r1 : r3;
            bf16x8 pb = pu.v;   // B-layout: n=q=l16, k=key=quad*8+j

            bf16x8 vf[4];
#pragma unroll
            for (int nt = 0; nt < 4; ++nt)
                vf[nt] = ldbf8(&Vb[b * 2048 + nt * 512 + lane * 8]);  // A: m=d, k=key
#pragma unroll
            for (int nt = 0; nt < 4; ++nt)
                oacc[b][nt] = mfma16(vf[nt], pb, oacc[b][nt]);
        }

        __syncthreads();  // drains vmcnt (prefetch landed) + all LDS reads done
        buf ^= 1;
    }

    // ---- epilogue: full-128B-line stores via per-wave LDS transpose ----
    // oacc layout: q=l16 (col), d=nt*16+quad*4+r (row) -> ep[q][d] index below.
    // loop's final barrier done: all staging/LDS traffic finished -> Kl dead.
    USHORT* part = kc ? pt1 : pt0;
    USHORT* ep = ((USHORT*)Kl) + wv * (16 * 72);  // 4 x 2.25KB <= 64KB
#pragma unroll
    for (int b = 0; b < 8; ++b) {
#pragma unroll
        for (int nt = 0; nt < 4; ++nt)
#pragma unroll
            for (int r = 0; r < 4; ++r)
                ep[l16 * 72 + nt * 16 + quad * 4 + r] = f2bf(oacc[b][nt][r]);
        lds_fence();  // ds_write -> ds_read (wave-private)
#pragma unroll
        for (int half = 0; half < 2; ++half) {
            int row = half * 8 + (lane >> 3);
            int seg = lane & 7;
            u16x8 v = *(const u16x8*)&ep[row * 72 + seg * 8];
            *(u16x8*)(part + (size_t)((b << 10) + q0 + row) * 512 + h * 64 + seg * 8) = v;
        }
        lds_fence();  // WAR: reads drained before next b overwrites tile
    }
}

extern "C" void kernel_launch(void* const* d_in, const int* in_sizes, int n_in,
                              void* d_out, int out_size, void* d_ws, size_t ws_size,
                              hipStream_t stream) {
    const float* X = (const float*)d_in[0];     // (8,1024,512)
    const float* Wqkv = (const float*)d_in[1];  // (512,1536) — only cols 0..639 used
    const float* Wout = (const float*)d_in[2];  // (512,512)
    float* out = (float*)d_out;                 // (8,1024,512) fp32

    char* w = (char*)d_ws;
    USHORT* Xb  = (USHORT*)(w);              //  8,388,608 B (reused as parts[0]/CtxB)
    USHORT* Wt1 = (USHORT*)(w + 8388608);    //    655,360 B  (640x512)
    USHORT* Wt3 = (USHORT*)(w + 9043968);    //    524,288 B  (512x512)
    USHORT* P   = (USHORT*)(w + 9568256);    // 10,485,760 B  (8192x640 bf16)
    USHORT* Vt  = (USHORT*)(w + 20054016);   //  8,388,608 B  (8x8x64x1024 bf16)
    USHORT* pt1 = (USHORT*)(w + 28442624);   //  8,388,608 B  partial ctx (kc=1)
    USHORT* pt0 = Xb;                        // Xb dead after GEMM1; also reduce2 output
    USHORT* CtxB = Xb;

    prep_kernel<<<4352, 256, 0, stream>>>(X, Wqkv, Wout, Xb, Wt1, Wt3);
    // P = Xb @ Wqkv[:, :640]
    gemm_bt<true><<<dim3(64, 5), 256, 0, stream>>>(Xb, Wt1, (void*)P, 8192, 640, 512);
    transpose_v<<<dim3(16, 8, 8), 256, 0, stream>>>(P, Vt);
    attn_kernel<<<256, 256, 0, stream>>>(P, Vt, pt0, pt1);
    // CtxB = pt0 + pt1 (in-place over pt0, fp32 accumulation)
    reduce2<<<2048, 256, 0, stream>>>(pt0, pt1, CtxB);
    // out = ctx @ W_out
    gemm_bt<false><<<dim3(64, 4), 256, 0, stream>>>(CtxB, Wt3, (void*)out, 8192, 512, 512);
}